// Round 1
// baseline (1233.346 us; speedup 1.0000x reference)
//
#include <hip/hip_runtime.h>
#include <hip/hip_bf16.h>

// HypLoRA: out = x@W^T + b + 2 * scale2(row) * (u(row) @ B)
//   u(row)    = s1 * (x_row @ A), s1 = min(||x||,1.5)/max(||x||,EPS)
//   scale2    = min(n2,1.5)/max(n2,EPS),  n2^2 = u^T (B B^T) u
// K = clip(exp(log_K),...) cancels identically in log(exp(.)) at origin.

#define DD 4096
#define MR 8192
#define BM 128
#define BN 128
#define BK 32

typedef float f32x4 __attribute__((ext_vector_type(4)));
typedef __bf16 bf16x8 __attribute__((ext_vector_type(8)));

#define GLOAD_LDS16(gptr, lptr)                                                        \
  __builtin_amdgcn_global_load_lds((const __attribute__((address_space(1))) void*)(gptr), \
                                   (__attribute__((address_space(3))) void*)(lptr), 16, 0, 0)

__device__ __forceinline__ __bf16 f2bf(float f) { return (__bf16)f; }

// ---------------- W f32 -> bf16 ----------------
__global__ __launch_bounds__(256) void k_convW(const float* __restrict__ src,
                                               __bf16* __restrict__ dst) {
  int i = blockIdx.x * 256 + threadIdx.x;  // 8192 blocks * 256 = 2M vecs of 8
  const f32x4* s = reinterpret_cast<const f32x4*>(src) + (size_t)i * 2;
  f32x4 v0 = s[0], v1 = s[1];
  bf16x8 o;
  o[0] = f2bf(v0[0]); o[1] = f2bf(v0[1]); o[2] = f2bf(v0[2]); o[3] = f2bf(v0[3]);
  o[4] = f2bf(v1[0]); o[5] = f2bf(v1[1]); o[6] = f2bf(v1[2]); o[7] = f2bf(v1[3]);
  reinterpret_cast<bf16x8*>(dst)[i] = o;
}

// ---------------- G = B B^T (8x8) ----------------
__global__ __launch_bounds__(256) void k_G(const float* __restrict__ Bm,
                                           float* __restrict__ G) {
  int t = threadIdx.x;
  float g[64];
#pragma unroll
  for (int i = 0; i < 64; ++i) g[i] = 0.f;
  for (int d = t; d < DD; d += 256) {
    float br[8];
#pragma unroll
    for (int r = 0; r < 8; ++r) br[r] = Bm[r * DD + d];
#pragma unroll
    for (int r = 0; r < 8; ++r)
#pragma unroll
      for (int s = 0; s < 8; ++s) g[r * 8 + s] += br[r] * br[s];
  }
  int lane = t & 63, wid = t >> 6;
  __shared__ float gs[4][64];
#pragma unroll
  for (int i = 0; i < 64; ++i) {
    float v = g[i];
    for (int off = 32; off >= 1; off >>= 1) v += __shfl_down(v, off, 64);
    if (lane == 0) gs[wid][i] = v;
  }
  __syncthreads();
  if (t < 64) G[t] = gs[0][t] + gs[1][t] + gs[2][t] + gs[3][t];
}

// ---------------- per-row: norm, x@A, scale chain, x->bf16 ----------------
__global__ __launch_bounds__(256) void k_rows(const float* __restrict__ x,
                                              const float* __restrict__ A,
                                              const float* __restrict__ G,
                                              float* __restrict__ Cc,
                                              __bf16* __restrict__ Xb) {
  int row = blockIdx.x;
  const float* xr = x + (size_t)row * DD;
  __bf16* xbr = Xb + (size_t)row * DD;
  int t = threadIdx.x;
  float nsq = 0.f;
  float p[8] = {0, 0, 0, 0, 0, 0, 0, 0};
#pragma unroll
  for (int i = 0; i < 16; ++i) {
    int d = t + 256 * i;
    float xv = xr[d];
    xbr[d] = f2bf(xv);
    nsq += xv * xv;
    f32x4 a0 = *reinterpret_cast<const f32x4*>(A + (size_t)d * 8);
    f32x4 a1 = *reinterpret_cast<const f32x4*>(A + (size_t)d * 8 + 4);
    p[0] += xv * a0[0]; p[1] += xv * a0[1]; p[2] += xv * a0[2]; p[3] += xv * a0[3];
    p[4] += xv * a1[0]; p[5] += xv * a1[1]; p[6] += xv * a1[2]; p[7] += xv * a1[3];
  }
  for (int off = 32; off >= 1; off >>= 1) {
    nsq += __shfl_down(nsq, off, 64);
#pragma unroll
    for (int r = 0; r < 8; ++r) p[r] += __shfl_down(p[r], off, 64);
  }
  __shared__ float red[4][9];
  int lane = t & 63, wid = t >> 6;
  if (lane == 0) {
    red[wid][0] = nsq;
#pragma unroll
    for (int r = 0; r < 8; ++r) red[wid][1 + r] = p[r];
  }
  __syncthreads();
  if (t == 0) {
    float ns = red[0][0] + red[1][0] + red[2][0] + red[3][0];
    float u[8];
#pragma unroll
    for (int r = 0; r < 8; ++r)
      u[r] = red[0][1 + r] + red[1][1 + r] + red[2][1 + r] + red[3][1 + r];
    float n = sqrtf(ns);
    float s1 = fminf(n, 1.5f) / fmaxf(n, 1e-7f);
#pragma unroll
    for (int r = 0; r < 8; ++r) u[r] *= s1;
    float n2sq = 0.f;
#pragma unroll
    for (int r = 0; r < 8; ++r)
#pragma unroll
      for (int s = 0; s < 8; ++s) n2sq += u[r] * u[s] * G[r * 8 + s];
    float n2 = sqrtf(fmaxf(n2sq, 0.f));
    float sc2 = fminf(n2, 1.5f) / fmaxf(n2, 1e-7f);
#pragma unroll
    for (int r = 0; r < 8; ++r) Cc[(size_t)row * 8 + r] = 2.0f * sc2 * u[r];
  }
}

// ---------------- main GEMM: out = Xb@Wb^T + bias + c @ B ----------------
__global__ __launch_bounds__(256) void k_gemm(const __bf16* __restrict__ Xb,
                                              const __bf16* __restrict__ Wb,
                                              const float* __restrict__ bias,
                                              const float* __restrict__ Cc,
                                              const float* __restrict__ Bm,
                                              float* __restrict__ out) {
  __shared__ union {
    struct { __bf16 As[BM][BK]; __bf16 Bs[BN][BK]; } tiles;   // 16 KB
    struct { float cs[BM][8]; float bs2[8][BN]; } epi;        // 8 KB
  } sm;

  const int nwg = (MR / BM) * (DD / BN);  // 2048, %8==0 -> simple swizzle bijective
  int wg = ((int)blockIdx.x % 8) * (nwg / 8) + (int)blockIdx.x / 8;
  int tm = wg / (DD / BN);
  int tn = wg % (DD / BN);
  int row0 = tm * BM, col0 = tn * BN;

  int t = threadIdx.x;
  int lane = t & 63, wid = t >> 6;
  int wm = wid >> 1, wn = wid & 1;         // 2x2 waves, 64x64 each
  int fr = lane & 15;
  int ko = (lane >> 4) * 8;

  f32x4 acc[4][4] = {};

  // staging: chunk ci (0..511) -> LDS row ci>>2, col (ci&3)*8 ; thread owns ci=t and t+256
  const __bf16* gA = Xb + (size_t)(row0 + (t >> 2)) * DD + (t & 3) * 8;
  const __bf16* gA2 = gA + (size_t)64 * DD;
  const __bf16* gB = Wb + (size_t)(col0 + (t >> 2)) * DD + (t & 3) * 8;
  const __bf16* gB2 = gB + (size_t)64 * DD;
  char* ldsA = (char*)(&sm.tiles.As[0][0]) + t * 16;
  char* ldsA2 = ldsA + 256 * 16;
  char* ldsB = (char*)(&sm.tiles.Bs[0][0]) + t * 16;
  char* ldsB2 = ldsB + 256 * 16;

  for (int k0 = 0; k0 < DD; k0 += BK) {
    GLOAD_LDS16(gA + k0, ldsA);
    GLOAD_LDS16(gA2 + k0, ldsA2);
    GLOAD_LDS16(gB + k0, ldsB);
    GLOAD_LDS16(gB2 + k0, ldsB2);
    __syncthreads();  // compiler emits vmcnt(0) drain before barrier

    bf16x8 aF[4], bF[4];
#pragma unroll
    for (int fm = 0; fm < 4; ++fm)
      aF[fm] = *reinterpret_cast<const bf16x8*>(&sm.tiles.As[wm * 64 + fm * 16 + fr][ko]);
#pragma unroll
    for (int fn = 0; fn < 4; ++fn)
      bF[fn] = *reinterpret_cast<const bf16x8*>(&sm.tiles.Bs[wn * 64 + fn * 16 + fr][ko]);
#pragma unroll
    for (int fm = 0; fm < 4; ++fm)
#pragma unroll
      for (int fn = 0; fn < 4; ++fn)
        acc[fm][fn] = __builtin_amdgcn_mfma_f32_16x16x32_bf16(aF[fm], bF[fn], acc[fm][fn], 0, 0, 0);
    __syncthreads();
  }

  // ---- epilogue: stage c[128][8] and B[8][128] slices in LDS ----
  {
    f32x4 cv = *reinterpret_cast<const f32x4*>(Cc + (size_t)row0 * 8 + t * 4);
    *reinterpret_cast<f32x4*>(&sm.epi.cs[0][0] + t * 4) = cv;
    int rr = t >> 5;
    int cc = (t & 31) * 4;
    f32x4 bv = *reinterpret_cast<const f32x4*>(Bm + (size_t)rr * DD + col0 + cc);
    *reinterpret_cast<f32x4*>(&sm.epi.bs2[0][0] + rr * 128 + cc) = bv;
  }
  __syncthreads();

  int coll = wn * 64 + fr;
  float biasv[4], bcol[4][8];
#pragma unroll
  for (int fn = 0; fn < 4; ++fn) {
    biasv[fn] = bias[col0 + coll + fn * 16];
#pragma unroll
    for (int r = 0; r < 8; ++r) bcol[fn][r] = sm.epi.bs2[r][coll + fn * 16];
  }
#pragma unroll
  for (int fm = 0; fm < 4; ++fm) {
#pragma unroll
    for (int j = 0; j < 4; ++j) {
      int rl = wm * 64 + fm * 16 + (lane >> 4) * 4 + j;
      float c0 = sm.epi.cs[rl][0], c1 = sm.epi.cs[rl][1], c2 = sm.epi.cs[rl][2],
            c3 = sm.epi.cs[rl][3], c4 = sm.epi.cs[rl][4], c5 = sm.epi.cs[rl][5],
            c6 = sm.epi.cs[rl][6], c7 = sm.epi.cs[rl][7];
#pragma unroll
      for (int fn = 0; fn < 4; ++fn) {
        float delta = c0 * bcol[fn][0] + c1 * bcol[fn][1] + c2 * bcol[fn][2] +
                      c3 * bcol[fn][3] + c4 * bcol[fn][4] + c5 * bcol[fn][5] +
                      c6 * bcol[fn][6] + c7 * bcol[fn][7];
        out[(size_t)(row0 + rl) * DD + col0 + coll + fn * 16] =
            acc[fm][fn][j] + biasv[fn] + delta;
      }
    }
  }
}

extern "C" void kernel_launch(void* const* d_in, const int* in_sizes, int n_in,
                              void* d_out, int out_size, void* d_ws, size_t ws_size,
                              hipStream_t stream) {
  const float* x = (const float*)d_in[0];   // [4,2048,4096]
  const float* W = (const float*)d_in[1];   // [4096,4096]
  const float* b = (const float*)d_in[2];   // [4096]
  const float* A = (const float*)d_in[3];   // [4096,8]
  const float* Bm = (const float*)d_in[4];  // [8,4096]
  // d_in[5] = log_K : K cancels analytically, unused.
  float* out = (float*)d_out;

  char* ws = (char*)d_ws;
  __bf16* Xb = (__bf16*)ws;                                    // 64 MB
  __bf16* Wb = (__bf16*)(ws + (size_t)64 * 1024 * 1024);       // 32 MB
  float* Cc = (float*)(ws + (size_t)96 * 1024 * 1024);         // 256 KB
  float* G = (float*)(ws + (size_t)96 * 1024 * 1024 + 256 * 1024);

  k_convW<<<8192, 256, 0, stream>>>(W, Wb);
  k_G<<<1, 256, 0, stream>>>(Bm, G);
  k_rows<<<MR, 256, 0, stream>>>(x, A, G, Cc, Xb);
  k_gemm<<<(MR / BM) * (DD / BN), 256, 0, stream>>>(Xb, Wb, b, Cc, Bm, out);
}

// Round 2
// 465.734 us; speedup vs baseline: 2.6482x; 2.6482x over previous
//
#include <hip/hip_runtime.h>
#include <hip/hip_bf16.h>

// HypLoRA: out = x@W^T + b + 2 * scale2(row) * (u(row) @ B)
//   u(row)    = s1 * (x_row @ A), s1 = min(||x||,1.5)/max(||x||,EPS)
//   scale2    = min(n2,1.5)/max(n2,EPS),  n2^2 = u^T (B B^T) u
// K = clip(exp(log_K),...) cancels identically in log(exp(.)) at origin.

#define DD 4096
#define MR 8192
#define BM 128
#define BN 128
#define BK 64

typedef float f32x4 __attribute__((ext_vector_type(4)));
typedef __bf16 bf16x8 __attribute__((ext_vector_type(8)));

#define GLOAD_LDS16(gptr, lptr)                                                        \
  __builtin_amdgcn_global_load_lds((const __attribute__((address_space(1))) void*)(gptr), \
                                   (__attribute__((address_space(3))) void*)(lptr), 16, 0, 0)

__device__ __forceinline__ __bf16 f2bf(float f) { return (__bf16)f; }

// ---------------- W f32 -> bf16 ----------------
__global__ __launch_bounds__(256) void k_convW(const float* __restrict__ src,
                                               __bf16* __restrict__ dst) {
  int i = blockIdx.x * 256 + threadIdx.x;
  const f32x4* s = reinterpret_cast<const f32x4*>(src) + (size_t)i * 2;
  f32x4 v0 = s[0], v1 = s[1];
  bf16x8 o;
  o[0] = f2bf(v0[0]); o[1] = f2bf(v0[1]); o[2] = f2bf(v0[2]); o[3] = f2bf(v0[3]);
  o[4] = f2bf(v1[0]); o[5] = f2bf(v1[1]); o[6] = f2bf(v1[2]); o[7] = f2bf(v1[3]);
  reinterpret_cast<bf16x8*>(dst)[i] = o;
}

// ---------------- G = B B^T (8x8) ----------------
__global__ __launch_bounds__(256) void k_G(const float* __restrict__ Bm,
                                           float* __restrict__ G) {
  int t = threadIdx.x;
  float g[64];
#pragma unroll
  for (int i = 0; i < 64; ++i) g[i] = 0.f;
  for (int d = t; d < DD; d += 256) {
    float br[8];
#pragma unroll
    for (int r = 0; r < 8; ++r) br[r] = Bm[r * DD + d];
#pragma unroll
    for (int r = 0; r < 8; ++r)
#pragma unroll
      for (int s = 0; s < 8; ++s) g[r * 8 + s] += br[r] * br[s];
  }
  int lane = t & 63, wid = t >> 6;
  __shared__ float gs[4][64];
#pragma unroll
  for (int i = 0; i < 64; ++i) {
    float v = g[i];
    for (int off = 32; off >= 1; off >>= 1) v += __shfl_down(v, off, 64);
    if (lane == 0) gs[wid][i] = v;
  }
  __syncthreads();
  if (t < 64) G[t] = gs[0][t] + gs[1][t] + gs[2][t] + gs[3][t];
}

// ---------------- per-row: norm, x@A, scale chain, x->bf16 ----------------
__global__ __launch_bounds__(256) void k_rows(const float* __restrict__ x,
                                              const float* __restrict__ A,
                                              const float* __restrict__ G,
                                              float* __restrict__ Cc,
                                              __bf16* __restrict__ Xb) {
  int row = blockIdx.x;
  const float* xr = x + (size_t)row * DD;
  __bf16* xbr = Xb + (size_t)row * DD;
  int t = threadIdx.x;
  float nsq = 0.f;
  float p[8] = {0, 0, 0, 0, 0, 0, 0, 0};
#pragma unroll
  for (int i = 0; i < 16; ++i) {
    int d = t + 256 * i;
    float xv = xr[d];
    xbr[d] = f2bf(xv);
    nsq += xv * xv;
    f32x4 a0 = *reinterpret_cast<const f32x4*>(A + (size_t)d * 8);
    f32x4 a1 = *reinterpret_cast<const f32x4*>(A + (size_t)d * 8 + 4);
    p[0] += xv * a0[0]; p[1] += xv * a0[1]; p[2] += xv * a0[2]; p[3] += xv * a0[3];
    p[4] += xv * a1[0]; p[5] += xv * a1[1]; p[6] += xv * a1[2]; p[7] += xv * a1[3];
  }
  for (int off = 32; off >= 1; off >>= 1) {
    nsq += __shfl_down(nsq, off, 64);
#pragma unroll
    for (int r = 0; r < 8; ++r) p[r] += __shfl_down(p[r], off, 64);
  }
  __shared__ float red[4][9];
  int lane = t & 63, wid = t >> 6;
  if (lane == 0) {
    red[wid][0] = nsq;
#pragma unroll
    for (int r = 0; r < 8; ++r) red[wid][1 + r] = p[r];
  }
  __syncthreads();
  if (t == 0) {
    float ns = red[0][0] + red[1][0] + red[2][0] + red[3][0];
    float u[8];
#pragma unroll
    for (int r = 0; r < 8; ++r)
      u[r] = red[0][1 + r] + red[1][1 + r] + red[2][1 + r] + red[3][1 + r];
    float n = sqrtf(ns);
    float s1 = fminf(n, 1.5f) / fmaxf(n, 1e-7f);
#pragma unroll
    for (int r = 0; r < 8; ++r) u[r] *= s1;
    float n2sq = 0.f;
#pragma unroll
    for (int r = 0; r < 8; ++r)
#pragma unroll
      for (int s = 0; s < 8; ++s) n2sq += u[r] * u[s] * G[r * 8 + s];
    float n2 = sqrtf(fmaxf(n2sq, 0.f));
    float sc2 = fminf(n2, 1.5f) / fmaxf(n2, 1e-7f);
#pragma unroll
    for (int r = 0; r < 8; ++r) Cc[(size_t)row * 8 + r] = 2.0f * sc2 * u[r];
  }
}

// ---------------- main GEMM: out = Xb@Wb^T + bias + c @ B ----------------
// LDS tiles [128][BK=64] bf16, 128B rows. T2 XOR swizzle (both sides, rule #21):
//   phys_byte = logical_byte ^ ((row&7)<<4)
// Write side: global_load_lds linear dest; SOURCE fetches the inverse-swizzled
// logical element (involution -> same formula). Read side: fragment slot
// (ks*4+hi)^(fr&7) -> 16 lanes over 8 slots = 2-way = free (m136).
__global__ __launch_bounds__(256) void k_gemm(const __bf16* __restrict__ Xb,
                                              const __bf16* __restrict__ Wb,
                                              const float* __restrict__ bias,
                                              const float* __restrict__ Cc,
                                              const float* __restrict__ Bm,
                                              float* __restrict__ out) {
  __shared__ union {
    struct { __bf16 As[BM][BK]; __bf16 Bs[BN][BK]; } tiles;   // 32 KB
    struct { float cs[BM][8]; float bs2[8][BN]; } epi;        // 8 KB
  } sm;

  const int nwg = (MR / BM) * (DD / BN);  // 2048, %8==0 -> swizzle bijective
  int wg = ((int)blockIdx.x % 8) * (nwg / 8) + (int)blockIdx.x / 8;
  int tm = wg / (DD / BN);
  int tn = wg % (DD / BN);
  int row0 = tm * BM, col0 = tn * BN;

  int t = threadIdx.x;
  int lane = t & 63, wid = t >> 6;
  int wm = wid >> 1, wn = wid & 1;         // 2x2 waves, 64x64 each
  int fr = lane & 15;
  int hi = lane >> 4;                       // k-group 0..3
  int fr7 = fr & 7;

  f32x4 acc[4][4] = {};

  // staging constants: thread t, chunk i in [0,4):
  //   LDS phys chunk = i*256+t -> row = 32*i + (t>>3), slot = t&7
  //   logical slot = (t&7) ^ ((t>>3)&7)   (row&7 == (t>>3)&7)
  int tr = t >> 3;
  int tsw = ((t & 7) ^ (tr & 7)) * 8;      // element offset in K
  const __bf16* gA = Xb + (size_t)(row0 + tr) * DD + tsw;
  const __bf16* gB = Wb + (size_t)(col0 + tr) * DD + tsw;
  char* ldsA = (char*)(&sm.tiles.As[0][0]) + t * 16;
  char* ldsB = (char*)(&sm.tiles.Bs[0][0]) + t * 16;
  const char* Ab = (const char*)(&sm.tiles.As[0][0]);
  const char* Bb = (const char*)(&sm.tiles.Bs[0][0]);

  for (int k0 = 0; k0 < DD; k0 += BK) {
#pragma unroll
    for (int i = 0; i < 4; ++i) {
      GLOAD_LDS16(gA + k0 + (size_t)(32 * i) * DD, ldsA + 4096 * i);
      GLOAD_LDS16(gB + k0 + (size_t)(32 * i) * DD, ldsB + 4096 * i);
    }
    __syncthreads();  // compiler drains vmcnt before barrier (m97 structure)

    bf16x8 aF[4][2], bF[4][2];
#pragma unroll
    for (int fm = 0; fm < 4; ++fm) {
      int row = wm * 64 + fm * 16 + fr;
#pragma unroll
      for (int ks = 0; ks < 2; ++ks)
        aF[fm][ks] = *reinterpret_cast<const bf16x8*>(
            Ab + row * 128 + ((((ks * 4 + hi) ^ fr7)) << 4));
    }
#pragma unroll
    for (int fn = 0; fn < 4; ++fn) {
      int row = wn * 64 + fn * 16 + fr;
#pragma unroll
      for (int ks = 0; ks < 2; ++ks)
        bF[fn][ks] = *reinterpret_cast<const bf16x8*>(
            Bb + row * 128 + ((((ks * 4 + hi) ^ fr7)) << 4));
    }
#pragma unroll
    for (int ks = 0; ks < 2; ++ks)
#pragma unroll
      for (int fm = 0; fm < 4; ++fm)
#pragma unroll
        for (int fn = 0; fn < 4; ++fn)
          acc[fm][fn] =
              __builtin_amdgcn_mfma_f32_16x16x32_bf16(aF[fm][ks], bF[fn][ks], acc[fm][fn], 0, 0, 0);
    __syncthreads();
  }

  // ---- epilogue: stage c[128][8] and B[8][128] slices in LDS ----
  {
    f32x4 cv = *reinterpret_cast<const f32x4*>(Cc + (size_t)row0 * 8 + t * 4);
    *reinterpret_cast<f32x4*>(&sm.epi.cs[0][0] + t * 4) = cv;
    int rr = t >> 5;
    int cc = (t & 31) * 4;
    f32x4 bv = *reinterpret_cast<const f32x4*>(Bm + (size_t)rr * DD + col0 + cc);
    *reinterpret_cast<f32x4*>(&sm.epi.bs2[0][0] + rr * 128 + cc) = bv;
  }
  __syncthreads();

  int coll = wn * 64 + fr;
  float biasv[4], bcol[4][8];
#pragma unroll
  for (int fn = 0; fn < 4; ++fn) {
    biasv[fn] = bias[col0 + coll + fn * 16];
#pragma unroll
    for (int r = 0; r < 8; ++r) bcol[fn][r] = sm.epi.bs2[r][coll + fn * 16];
  }
#pragma unroll
  for (int fm = 0; fm < 4; ++fm) {
#pragma unroll
    for (int j = 0; j < 4; ++j) {
      int rl = wm * 64 + fm * 16 + hi * 4 + j;
      float c0 = sm.epi.cs[rl][0], c1 = sm.epi.cs[rl][1], c2 = sm.epi.cs[rl][2],
            c3 = sm.epi.cs[rl][3], c4 = sm.epi.cs[rl][4], c5 = sm.epi.cs[rl][5],
            c6 = sm.epi.cs[rl][6], c7 = sm.epi.cs[rl][7];
#pragma unroll
      for (int fn = 0; fn < 4; ++fn) {
        float delta = c0 * bcol[fn][0] + c1 * bcol[fn][1] + c2 * bcol[fn][2] +
                      c3 * bcol[fn][3] + c4 * bcol[fn][4] + c5 * bcol[fn][5] +
                      c6 * bcol[fn][6] + c7 * bcol[fn][7];
        out[(size_t)(row0 + rl) * DD + col0 + coll + fn * 16] =
            acc[fm][fn][j] + biasv[fn] + delta;
      }
    }
  }
}

extern "C" void kernel_launch(void* const* d_in, const int* in_sizes, int n_in,
                              void* d_out, int out_size, void* d_ws, size_t ws_size,
                              hipStream_t stream) {
  const float* x = (const float*)d_in[0];   // [4,2048,4096]
  const float* W = (const float*)d_in[1];   // [4096,4096]
  const float* b = (const float*)d_in[2];   // [4096]
  const float* A = (const float*)d_in[3];   // [4096,8]
  const float* Bm = (const float*)d_in[4];  // [8,4096]
  // d_in[5] = log_K : K cancels analytically, unused.
  float* out = (float*)d_out;

  char* ws = (char*)d_ws;
  __bf16* Xb = (__bf16*)ws;                                    // 64 MB
  __bf16* Wb = (__bf16*)(ws + (size_t)64 * 1024 * 1024);       // 32 MB
  float* Cc = (float*)(ws + (size_t)96 * 1024 * 1024);         // 256 KB
  float* G = (float*)(ws + (size_t)96 * 1024 * 1024 + 256 * 1024);

  k_convW<<<8192, 256, 0, stream>>>(W, Wb);
  k_G<<<1, 256, 0, stream>>>(Bm, G);
  k_rows<<<MR, 256, 0, stream>>>(x, A, G, Cc, Xb);
  k_gemm<<<(MR / BM) * (DD / BN), 256, 0, stream>>>(Xb, Wb, b, Cc, Bm, out);
}

// Round 3
// 400.649 us; speedup vs baseline: 3.0784x; 1.1624x over previous
//
#include <hip/hip_runtime.h>
#include <hip/hip_bf16.h>

// HypLoRA: out = x@W^T + b + 2 * scale2(row) * (u(row) @ B)
//   u(row)    = s1 * (x_row @ A), s1 = min(||x||,1.5)/max(||x||,EPS)
//   scale2    = min(n2,1.5)/max(n2,EPS),  n2^2 = u^T (B B^T) u
// K = clip(exp(log_K),...) cancels identically in log(exp(.)) at origin.
//
// GEMM: 256x256 tile, BK=64, 8 waves (2Mx4N), 8-phase schedule (T3+T4+T5):
// raw s_barrier (no vmcnt drain), counted vmcnt(6) at phases 4/8 only,
// setprio around MFMA quadrants. LDS regions [256][32] bf16 (64B rows) make
// wave fragment reads contiguous 1KB blocks -> bank-conflict-free, no swizzle.

#define DD 4096
#define MR 8192
#define BM 256
#define BN 256
#define BK 64

typedef float f32x4 __attribute__((ext_vector_type(4)));
typedef __bf16 bf16x8 __attribute__((ext_vector_type(8)));

#define GLOAD_LDS16(gptr, lptr)                                                        \
  __builtin_amdgcn_global_load_lds((const __attribute__((address_space(1))) void*)(gptr), \
                                   (__attribute__((address_space(3))) void*)(lptr), 16, 0, 0)

__device__ __forceinline__ __bf16 f2bf(float f) { return (__bf16)f; }

// ---------------- W f32 -> bf16 ----------------
__global__ __launch_bounds__(256) void k_convW(const float* __restrict__ src,
                                               __bf16* __restrict__ dst) {
  int i = blockIdx.x * 256 + threadIdx.x;
  const f32x4* s = reinterpret_cast<const f32x4*>(src) + (size_t)i * 2;
  f32x4 v0 = s[0], v1 = s[1];
  bf16x8 o;
  o[0] = f2bf(v0[0]); o[1] = f2bf(v0[1]); o[2] = f2bf(v0[2]); o[3] = f2bf(v0[3]);
  o[4] = f2bf(v1[0]); o[5] = f2bf(v1[1]); o[6] = f2bf(v1[2]); o[7] = f2bf(v1[3]);
  reinterpret_cast<bf16x8*>(dst)[i] = o;
}

// ---------------- G = B B^T (8x8) ----------------
__global__ __launch_bounds__(256) void k_G(const float* __restrict__ Bm,
                                           float* __restrict__ G) {
  int t = threadIdx.x;
  float g[64];
#pragma unroll
  for (int i = 0; i < 64; ++i) g[i] = 0.f;
  for (int d = t; d < DD; d += 256) {
    float br[8];
#pragma unroll
    for (int r = 0; r < 8; ++r) br[r] = Bm[r * DD + d];
#pragma unroll
    for (int r = 0; r < 8; ++r)
#pragma unroll
      for (int s = 0; s < 8; ++s) g[r * 8 + s] += br[r] * br[s];
  }
  int lane = t & 63, wid = t >> 6;
  __shared__ float gs[4][64];
#pragma unroll
  for (int i = 0; i < 64; ++i) {
    float v = g[i];
    for (int off = 32; off >= 1; off >>= 1) v += __shfl_down(v, off, 64);
    if (lane == 0) gs[wid][i] = v;
  }
  __syncthreads();
  if (t < 64) G[t] = gs[0][t] + gs[1][t] + gs[2][t] + gs[3][t];
}

// ---------------- per-row: norm, x@A, scale chain, x->bf16 ----------------
__global__ __launch_bounds__(256) void k_rows(const float* __restrict__ x,
                                              const float* __restrict__ A,
                                              const float* __restrict__ G,
                                              float* __restrict__ Cc,
                                              __bf16* __restrict__ Xb) {
  int row = blockIdx.x;
  const float* xr = x + (size_t)row * DD;
  __bf16* xbr = Xb + (size_t)row * DD;
  int t = threadIdx.x;
  float nsq = 0.f;
  float p[8] = {0, 0, 0, 0, 0, 0, 0, 0};
#pragma unroll
  for (int i = 0; i < 16; ++i) {
    int d = t + 256 * i;
    float xv = xr[d];
    xbr[d] = f2bf(xv);
    nsq += xv * xv;
    f32x4 a0 = *reinterpret_cast<const f32x4*>(A + (size_t)d * 8);
    f32x4 a1 = *reinterpret_cast<const f32x4*>(A + (size_t)d * 8 + 4);
    p[0] += xv * a0[0]; p[1] += xv * a0[1]; p[2] += xv * a0[2]; p[3] += xv * a0[3];
    p[4] += xv * a1[0]; p[5] += xv * a1[1]; p[6] += xv * a1[2]; p[7] += xv * a1[3];
  }
  for (int off = 32; off >= 1; off >>= 1) {
    nsq += __shfl_down(nsq, off, 64);
#pragma unroll
    for (int r = 0; r < 8; ++r) p[r] += __shfl_down(p[r], off, 64);
  }
  __shared__ float red[4][9];
  int lane = t & 63, wid = t >> 6;
  if (lane == 0) {
    red[wid][0] = nsq;
#pragma unroll
    for (int r = 0; r < 8; ++r) red[wid][1 + r] = p[r];
  }
  __syncthreads();
  if (t == 0) {
    float ns = red[0][0] + red[1][0] + red[2][0] + red[3][0];
    float u[8];
#pragma unroll
    for (int r = 0; r < 8; ++r)
      u[r] = red[0][1 + r] + red[1][1 + r] + red[2][1 + r] + red[3][1 + r];
    float n = sqrtf(ns);
    float s1 = fminf(n, 1.5f) / fmaxf(n, 1e-7f);
#pragma unroll
    for (int r = 0; r < 8; ++r) u[r] *= s1;
    float n2sq = 0.f;
#pragma unroll
    for (int r = 0; r < 8; ++r)
#pragma unroll
      for (int s = 0; s < 8; ++s) n2sq += u[r] * u[s] * G[r * 8 + s];
    float n2 = sqrtf(fmaxf(n2sq, 0.f));
    float sc2 = fminf(n2, 1.5f) / fmaxf(n2, 1e-7f);
#pragma unroll
    for (int r = 0; r < 8; ++r) Cc[(size_t)row * 8 + r] = 2.0f * sc2 * u[r];
  }
}

// ---------------- main GEMM: out = Xb@Wb^T + bias + c @ B ----------------
// LDS per buffer (64KB): [0,16K)=B.k0, [16K,32K)=A.k0, [32K,48K)=B.k1,
// [48K,64K)=A.k1; each region row-major [256 rows][32 K] bf16 (64B rows).
// Buffer 1 at +64KB. Region prefetch issue order (one region per phase) is
// >=1 phase after that region's last ds_read; each phase's lgkmcnt(0)
// precedes its end barrier, so a landing load can never corrupt a pending
// read. vmcnt(6) at phases 4/8 guarantees the next K-tile fully landed.
__global__ __launch_bounds__(512, 2) void k_gemm(const __bf16* __restrict__ Xb,
                                                 const __bf16* __restrict__ Wb,
                                                 const float* __restrict__ bias,
                                                 const float* __restrict__ Cc,
                                                 const float* __restrict__ Bm,
                                                 float* __restrict__ out) {
  __shared__ union {
    char raw[131072];
    struct { float cs[256][8]; float bs2[8][256]; } epi;
  } sm;
  char* smc = sm.raw;

  const int nwg = (MR / BM) * (DD / BN);  // 32*16 = 512, %8==0 -> bijective
  int wg = ((int)blockIdx.x % 8) * (nwg / 8) + (int)blockIdx.x / 8;
  int tm = wg / (DD / BN);
  int tn = wg % (DD / BN);
  int row0 = tm * BM, col0 = tn * BN;

  int t = threadIdx.x;
  int lane = t & 63, wid = t >> 6;
  int wm = wid >> 2, wn = wid & 3;  // 2x4 waves, each owns 128x64 of C
  int fr = lane & 15;
  int hi = lane >> 4;

  f32x4 acc[8][4] = {};
  bf16x8 aF[4], bF[4];

  // stage one 16KB region (tile tau, matrix half ks) -> ldsOff; 2 loads/thread
  auto STAGE = [&](const __bf16* mat, int rowbase, int tau, int ks, int ldsOff) {
    int kk = ((tau & 63) << 6) + (ks << 5) + ((t & 3) << 3);
    const __bf16* src = mat + (size_t)(rowbase + (t >> 2)) * DD + kk;
    char* dst = smc + ldsOff + t * 16;
    GLOAD_LDS16(src, dst);
    GLOAD_LDS16(src + (size_t)128 * DD, dst + 8192);
  };

#define LDA(buf, ks, mbase)                                                     \
  _Pragma("unroll") for (int j = 0; j < 4; ++j) aF[j] =                         \
      *reinterpret_cast<const bf16x8*>(smc + (buf)*65536 + 16384 + (ks)*32768 + \
                                       (wm * 128 + ((mbase) + j) * 16 + fr) * 64 + hi * 16);
#define LDB(buf, ks)                                                            \
  _Pragma("unroll") for (int j = 0; j < 4; ++j) bF[j] =                         \
      *reinterpret_cast<const bf16x8*>(smc + (buf)*65536 + (ks)*32768 +         \
                                       (wn * 64 + j * 16 + fr) * 64 + hi * 16);
#define MMQ(mbase)                                                              \
  __builtin_amdgcn_s_setprio(1);                                                \
  _Pragma("unroll") for (int j = 0; j < 4; ++j)                                 \
      _Pragma("unroll") for (int n = 0; n < 4; ++n)                             \
          acc[(mbase) + j][n] = __builtin_amdgcn_mfma_f32_16x16x32_bf16(        \
              aF[j], bF[n], acc[(mbase) + j][n], 0, 0, 0);                      \
  __builtin_amdgcn_s_setprio(0);
#define BAR() __builtin_amdgcn_s_barrier()
#define LGKM0() asm volatile("s_waitcnt lgkmcnt(0)" ::: "memory")

  // -------- prologue: tile0 all 4 regions, tile1 first 3 --------
  STAGE(Wb, col0, 0, 0, 0);
  STAGE(Xb, row0, 0, 0, 16384);
  STAGE(Wb, col0, 0, 1, 32768);
  STAGE(Xb, row0, 0, 1, 49152);
  asm volatile("s_waitcnt vmcnt(4)" ::: "memory");
  STAGE(Wb, col0, 1, 0, 65536 + 0);
  STAGE(Xb, row0, 1, 0, 65536 + 16384);
  STAGE(Wb, col0, 1, 1, 65536 + 32768);
  asm volatile("s_waitcnt vmcnt(6)" ::: "memory");  // tile0 fully landed
  BAR();

  for (int i = 0; i < DD / BK / 2; ++i) {
    int T = 2 * i;
    // P1: tile T, ks0, m0-3
    LDA(0, 0, 0); LDB(0, 0);
    STAGE(Xb, row0, T + 1, 1, 65536 + 49152);
    BAR(); LGKM0();
    MMQ(0);
    BAR();
    // P2: tile T, ks0, m4-7 (bF kept)
    LDA(0, 0, 4);
    STAGE(Wb, col0, T + 2, 0, 0);
    BAR(); LGKM0();
    MMQ(4);
    BAR();
    // P3: tile T, ks1, m0-3
    LDA(0, 1, 0); LDB(0, 1);
    STAGE(Xb, row0, T + 2, 0, 16384);
    BAR(); LGKM0();
    MMQ(0);
    BAR();
    // P4: tile T, ks1, m4-7
    LDA(0, 1, 4);
    STAGE(Wb, col0, T + 2, 1, 32768);
    BAR(); LGKM0();
    MMQ(4);
    asm volatile("s_waitcnt vmcnt(6)" ::: "memory");  // tile T+1 landed
    BAR();
    // P5: tile T+1, ks0, m0-3
    LDA(1, 0, 0); LDB(1, 0);
    STAGE(Xb, row0, T + 2, 1, 49152);
    BAR(); LGKM0();
    MMQ(0);
    BAR();
    // P6: tile T+1, ks0, m4-7
    LDA(1, 0, 4);
    STAGE(Wb, col0, T + 3, 0, 65536 + 0);
    BAR(); LGKM0();
    MMQ(4);
    BAR();
    // P7: tile T+1, ks1, m0-3
    LDA(1, 1, 0); LDB(1, 1);
    STAGE(Xb, row0, T + 3, 0, 65536 + 16384);
    BAR(); LGKM0();
    MMQ(0);
    BAR();
    // P8: tile T+1, ks1, m4-7
    LDA(1, 1, 4);
    STAGE(Wb, col0, T + 3, 1, 65536 + 32768);
    BAR(); LGKM0();
    MMQ(4);
    asm volatile("s_waitcnt vmcnt(6)" ::: "memory");  // tile T+2 landed
    BAR();
  }

  // -------- epilogue: drain DMA, reuse LDS for c[256][8] and B[8][256] ----
  asm volatile("s_waitcnt vmcnt(0)" ::: "memory");
  __syncthreads();
  reinterpret_cast<f32x4*>(&sm.epi.cs[0][0])[t] =
      *reinterpret_cast<const f32x4*>(Cc + (size_t)row0 * 8 + t * 4);
  {
    int rr = t >> 6, cc = (t & 63) * 4;
    *reinterpret_cast<f32x4*>(&sm.epi.bs2[rr][cc]) =
        *reinterpret_cast<const f32x4*>(Bm + (size_t)rr * DD + col0 + cc);
  }
  __syncthreads();

  int colb = col0 + wn * 64 + fr;
  float biasv[4], bcol[4][8];
#pragma unroll
  for (int n = 0; n < 4; ++n) {
    biasv[n] = bias[colb + n * 16];
#pragma unroll
    for (int r = 0; r < 8; ++r) bcol[n][r] = sm.epi.bs2[r][wn * 64 + fr + n * 16];
  }
#pragma unroll
  for (int m = 0; m < 8; ++m) {
#pragma unroll
    for (int j = 0; j < 4; ++j) {
      int rl = wm * 128 + m * 16 + hi * 4 + j;
      float c0 = sm.epi.cs[rl][0], c1 = sm.epi.cs[rl][1], c2 = sm.epi.cs[rl][2],
            c3 = sm.epi.cs[rl][3], c4 = sm.epi.cs[rl][4], c5 = sm.epi.cs[rl][5],
            c6 = sm.epi.cs[rl][6], c7 = sm.epi.cs[rl][7];
      float* orow = out + (size_t)(row0 + rl) * DD + colb;
#pragma unroll
      for (int n = 0; n < 4; ++n) {
        float delta = c0 * bcol[n][0] + c1 * bcol[n][1] + c2 * bcol[n][2] +
                      c3 * bcol[n][3] + c4 * bcol[n][4] + c5 * bcol[n][5] +
                      c6 * bcol[n][6] + c7 * bcol[n][7];
        orow[n * 16] = acc[m][n][j] + biasv[n] + delta;
      }
    }
  }
}

extern "C" void kernel_launch(void* const* d_in, const int* in_sizes, int n_in,
                              void* d_out, int out_size, void* d_ws, size_t ws_size,
                              hipStream_t stream) {
  const float* x = (const float*)d_in[0];   // [4,2048,4096]
  const float* W = (const float*)d_in[1];   // [4096,4096]
  const float* b = (const float*)d_in[2];   // [4096]
  const float* A = (const float*)d_in[3];   // [4096,8]
  const float* Bm = (const float*)d_in[4];  // [8,4096]
  // d_in[5] = log_K : K cancels analytically, unused.
  float* out = (float*)d_out;

  char* ws = (char*)d_ws;
  __bf16* Xb = (__bf16*)ws;                                    // 64 MB
  __bf16* Wb = (__bf16*)(ws + (size_t)64 * 1024 * 1024);       // 32 MB
  float* Cc = (float*)(ws + (size_t)96 * 1024 * 1024);         // 256 KB
  float* G = (float*)(ws + (size_t)96 * 1024 * 1024 + 256 * 1024);

  k_convW<<<8192, 256, 0, stream>>>(W, Wb);
  k_G<<<1, 256, 0, stream>>>(Bm, G);
  k_rows<<<MR, 256, 0, stream>>>(x, A, G, Cc, Xb);
  k_gemm<<<(MR / BM) * (DD / BN), 512, 0, stream>>>(Xb, Wb, b, Cc, Bm, out);
}

// Round 5
// 359.628 us; speedup vs baseline: 3.4295x; 1.1141x over previous
//
#include <hip/hip_runtime.h>
#include <hip/hip_bf16.h>

// HypLoRA: out = x@W^T + b + 2 * scale2(row) * (u(row) @ B)
//   u(row)    = s1 * (x_row @ A), s1 = min(||x||,1.5)/max(||x||,EPS)
//   scale2    = min(n2,1.5)/max(n2,EPS),  n2^2 = u^T (B B^T) u
// K = clip(exp(log_K),...) cancels identically in log(exp(.)) at origin.
//
// Launch 1 (k_prep, fused): G = B B^T | per-row u = s1*(x@A) + x->bf16 | W->bf16
// Launch 2 (k_gemm): 256x256 8-phase (T3+T4+T5), swizzled [256][32] LDS regions,
//                    epilogue computes c = 2*sc2*u from U,G and adds bias + c@B.

#define DD 4096
#define MR 8192
#define BM 256
#define BN 256
#define BK 64

typedef float f32x4 __attribute__((ext_vector_type(4)));
typedef __bf16 bf16x8 __attribute__((ext_vector_type(8)));

#define GLOAD_LDS16(gptr, lptr)                                                        \
  __builtin_amdgcn_global_load_lds((const __attribute__((address_space(1))) void*)(gptr), \
                                   (__attribute__((address_space(3))) void*)(lptr), 16, 0, 0)

__device__ __forceinline__ __bf16 f2bf(float f) { return (__bf16)f; }

// ---------------- fused prep ----------------
// bid 0                  : G = B B^T (8x8)
// bid [1, 1+8192)        : row r: u[r] = s1 * (x_r @ A); Xb = bf16(x)
// bid [1+8192, 1+16384)  : W -> bf16  (16.78M elems / (256 thr * 8) = 8192 blocks)
__global__ __launch_bounds__(256) void k_prep(const float* __restrict__ x,
                                              const float* __restrict__ W,
                                              const float* __restrict__ A,
                                              const float* __restrict__ Bm,
                                              __bf16* __restrict__ Xb,
                                              __bf16* __restrict__ Wb,
                                              float* __restrict__ U,
                                              float* __restrict__ G) {
  int bid = blockIdx.x;
  int t = threadIdx.x;
  int lane = t & 63, wid = t >> 6;

  if (bid == 0) {
    // ---- G = B B^T ----
    float g[64];
#pragma unroll
    for (int i = 0; i < 64; ++i) g[i] = 0.f;
    for (int d = t; d < DD; d += 256) {
      float br[8];
#pragma unroll
      for (int r = 0; r < 8; ++r) br[r] = Bm[r * DD + d];
#pragma unroll
      for (int r = 0; r < 8; ++r)
#pragma unroll
        for (int s = 0; s < 8; ++s) g[r * 8 + s] += br[r] * br[s];
    }
    __shared__ float gs[4][64];
#pragma unroll
    for (int i = 0; i < 64; ++i) {
      float v = g[i];
      for (int off = 32; off >= 1; off >>= 1) v += __shfl_down(v, off, 64);
      if (lane == 0) gs[wid][i] = v;
    }
    __syncthreads();
    if (t < 64) G[t] = gs[0][t] + gs[1][t] + gs[2][t] + gs[3][t];
  } else if (bid <= 8192) {
    // ---- per-row u + x->bf16 ----
    int row = bid - 1;
    const float* xr = x + (size_t)row * DD;
    __bf16* xbr = Xb + (size_t)row * DD;
    float nsq = 0.f;
    float p[8] = {0, 0, 0, 0, 0, 0, 0, 0};
#pragma unroll
    for (int i = 0; i < 16; ++i) {
      int d = t + 256 * i;
      float xv = xr[d];
      xbr[d] = f2bf(xv);
      nsq += xv * xv;
      f32x4 a0 = *reinterpret_cast<const f32x4*>(A + (size_t)d * 8);
      f32x4 a1 = *reinterpret_cast<const f32x4*>(A + (size_t)d * 8 + 4);
      p[0] += xv * a0[0]; p[1] += xv * a0[1]; p[2] += xv * a0[2]; p[3] += xv * a0[3];
      p[4] += xv * a1[0]; p[5] += xv * a1[1]; p[6] += xv * a1[2]; p[7] += xv * a1[3];
    }
    for (int off = 32; off >= 1; off >>= 1) {
      nsq += __shfl_down(nsq, off, 64);
#pragma unroll
      for (int r = 0; r < 8; ++r) p[r] += __shfl_down(p[r], off, 64);
    }
    __shared__ float red[4][9];
    if (lane == 0) {
      red[wid][0] = nsq;
#pragma unroll
      for (int r = 0; r < 8; ++r) red[wid][1 + r] = p[r];
    }
    __syncthreads();
    if (t == 0) {
      float ns = red[0][0] + red[1][0] + red[2][0] + red[3][0];
      float u[8];
#pragma unroll
      for (int r = 0; r < 8; ++r)
        u[r] = red[0][1 + r] + red[1][1 + r] + red[2][1 + r] + red[3][1 + r];
      float n = sqrtf(ns);
      float s1 = fminf(n, 1.5f) / fmaxf(n, 1e-7f);
#pragma unroll
      for (int r = 0; r < 8; ++r) U[(size_t)row * 8 + r] = s1 * u[r];
    }
  } else {
    // ---- W -> bf16 ----
    int i = (bid - 8193) * 256 + t;  // 8192 blocks -> 2M threads * 8 elems = 16.78M
    const f32x4* s = reinterpret_cast<const f32x4*>(W) + (size_t)i * 2;
    f32x4 v0 = s[0], v1 = s[1];
    bf16x8 o;
    o[0] = f2bf(v0[0]); o[1] = f2bf(v0[1]); o[2] = f2bf(v0[2]); o[3] = f2bf(v0[3]);
    o[4] = f2bf(v1[0]); o[5] = f2bf(v1[1]); o[6] = f2bf(v1[2]); o[7] = f2bf(v1[3]);
    reinterpret_cast<bf16x8*>(Wb)[i] = o;
  }
}

// ---------------- main GEMM: out = Xb@Wb^T + bias + c @ B ----------------
// LDS per buffer (64KB): [0,16K)=B.k0, [16K,32K)=A.k0, [32K,48K)=B.k1,
// [48K,64K)=A.k1; each region row-major [256 rows][32 K] bf16 (64B rows),
// T2 slot swizzle: phys_slot = logical_slot ^ ((row>>1)&3). 8 consecutive
// lanes of a fragment read then cover all 32 banks once -> conflict-free.
// Write side stays linear-dest (global_load_lds); the SOURCE k-offset is
// inverse-swizzled per thread: j = (t&3)^((t>>3)&3).
// vmcnt(6) at phases 4/8 only; raw s_barrier; setprio around MFMA (T4/T5).
__global__ __launch_bounds__(512, 2) void k_gemm(const __bf16* __restrict__ Xb,
                                                 const __bf16* __restrict__ Wb,
                                                 const float* __restrict__ bias,
                                                 const float* __restrict__ U,
                                                 const float* __restrict__ G,
                                                 const float* __restrict__ Bm,
                                                 float* __restrict__ out) {
  __shared__ union {
    char raw[131072];
    struct { float cs[256][8]; float bs2[8][256]; } epi;
  } sm;
  char* smc = sm.raw;

  const int nwg = (MR / BM) * (DD / BN);  // 32*16 = 512, %8==0 -> bijective
  int wg = ((int)blockIdx.x % 8) * (nwg / 8) + (int)blockIdx.x / 8;
  int tm = wg / (DD / BN);
  int tn = wg % (DD / BN);
  int row0 = tm * BM, col0 = tn * BN;

  int t = threadIdx.x;
  int lane = t & 63, wid = t >> 6;
  int wm = wid >> 2, wn = wid & 3;  // 2x4 waves, each owns 128x64 of C
  int fr = lane & 15;
  int hi = lane >> 4;
  int sw = (fr >> 1) & 3;  // read-side swizzle key

  f32x4 acc[8][4] = {};
  bf16x8 aF[4], bF[4];

  // stage one 16KB region (tile tau, K-half ks) -> ldsOff; 2 loads/thread.
  // source k-offset carries the inverse slot swizzle j = (t&3)^((t>>3)&3).
  auto STAGE = [&](const __bf16* mat, int rowbase, int tau, int ks, int ldsOff) {
    int j = (t & 3) ^ ((t >> 3) & 3);
    int kk = ((tau & 63) << 6) + (ks << 5) + (j << 3);
    const __bf16* src = mat + (size_t)(rowbase + (t >> 2)) * DD + kk;
    char* dst = smc + ldsOff + t * 16;
    GLOAD_LDS16(src, dst);
    GLOAD_LDS16(src + (size_t)128 * DD, dst + 8192);
  };

#define LDA(buf, ks, mbase)                                                     \
  _Pragma("unroll") for (int j = 0; j < 4; ++j) aF[j] =                         \
      *reinterpret_cast<const bf16x8*>(smc + (buf)*65536 + 16384 + (ks)*32768 + \
                                       (wm * 128 + ((mbase) + j) * 16 + fr) * 64 + \
                                       ((hi ^ sw) << 4));
#define LDB(buf, ks)                                                            \
  _Pragma("unroll") for (int j = 0; j < 4; ++j) bF[j] =                         \
      *reinterpret_cast<const bf16x8*>(smc + (buf)*65536 + (ks)*32768 +         \
                                       (wn * 64 + j * 16 + fr) * 64 +           \
                                       ((hi ^ sw) << 4));
#define MMQ(mbase)                                                              \
  __builtin_amdgcn_s_setprio(1);                                                \
  _Pragma("unroll") for (int j = 0; j < 4; ++j)                                 \
      _Pragma("unroll") for (int n = 0; n < 4; ++n)                             \
          acc[(mbase) + j][n] = __builtin_amdgcn_mfma_f32_16x16x32_bf16(        \
              aF[j], bF[n], acc[(mbase) + j][n], 0, 0, 0);                      \
  __builtin_amdgcn_s_setprio(0);
#define BAR() __builtin_amdgcn_s_barrier()
#define LGKM0() asm volatile("s_waitcnt lgkmcnt(0)" ::: "memory")

  // -------- prologue: tile0 all 4 regions, tile1 first 3 --------
  STAGE(Wb, col0, 0, 0, 0);
  STAGE(Xb, row0, 0, 0, 16384);
  STAGE(Wb, col0, 0, 1, 32768);
  STAGE(Xb, row0, 0, 1, 49152);
  asm volatile("s_waitcnt vmcnt(4)" ::: "memory");
  STAGE(Wb, col0, 1, 0, 65536 + 0);
  STAGE(Xb, row0, 1, 0, 65536 + 16384);
  STAGE(Wb, col0, 1, 1, 65536 + 32768);
  asm volatile("s_waitcnt vmcnt(6)" ::: "memory");  // tile0 fully landed
  BAR();

  for (int i = 0; i < DD / BK / 2; ++i) {
    int T = 2 * i;
    // P1: tile T, ks0, m0-3
    LDA(0, 0, 0); LDB(0, 0);
    STAGE(Xb, row0, T + 1, 1, 65536 + 49152);
    BAR(); LGKM0();
    MMQ(0);
    BAR();
    // P2: tile T, ks0, m4-7 (bF kept)
    LDA(0, 0, 4);
    STAGE(Wb, col0, T + 2, 0, 0);
    BAR(); LGKM0();
    MMQ(4);
    BAR();
    // P3: tile T, ks1, m0-3
    LDA(0, 1, 0); LDB(0, 1);
    STAGE(Xb, row0, T + 2, 0, 16384);
    BAR(); LGKM0();
    MMQ(0);
    BAR();
    // P4: tile T, ks1, m4-7
    LDA(0, 1, 4);
    STAGE(Wb, col0, T + 2, 1, 32768);
    BAR(); LGKM0();
    MMQ(4);
    asm volatile("s_waitcnt vmcnt(6)" ::: "memory");  // tile T+1 landed
    BAR();
    // P5: tile T+1, ks0, m0-3
    LDA(1, 0, 0); LDB(1, 0);
    STAGE(Xb, row0, T + 2, 1, 49152);
    BAR(); LGKM0();
    MMQ(0);
    BAR();
    // P6: tile T+1, ks0, m4-7
    LDA(1, 0, 4);
    STAGE(Wb, col0, T + 3, 0, 65536 + 0);
    BAR(); LGKM0();
    MMQ(4);
    BAR();
    // P7: tile T+1, ks1, m0-3
    LDA(1, 1, 0); LDB(1, 1);
    STAGE(Xb, row0, T + 3, 0, 65536 + 16384);
    BAR(); LGKM0();
    MMQ(0);
    BAR();
    // P8: tile T+1, ks1, m4-7
    LDA(1, 1, 4);
    STAGE(Wb, col0, T + 3, 1, 65536 + 32768);
    BAR(); LGKM0();
    MMQ(4);
    asm volatile("s_waitcnt vmcnt(6)" ::: "memory");  // tile T+2 landed
    BAR();
  }

  // -------- epilogue: drain DMA, compute c from U,G; stage B slice --------
  asm volatile("s_waitcnt vmcnt(0)" ::: "memory");
  __syncthreads();
  {
    int rr = t >> 6, cc = (t & 63) * 4;
    *reinterpret_cast<f32x4*>(&sm.epi.bs2[rr][cc]) =
        *reinterpret_cast<const f32x4*>(Bm + (size_t)rr * DD + col0 + cc);
  }
  if (t < 256) {
    f32x4 u0 = *reinterpret_cast<const f32x4*>(U + (size_t)(row0 + t) * 8);
    f32x4 u1 = *reinterpret_cast<const f32x4*>(U + (size_t)(row0 + t) * 8 + 4);
    float u[8] = {u0[0], u0[1], u0[2], u0[3], u1[0], u1[1], u1[2], u1[3]};
    float n2sq = 0.f;
#pragma unroll
    for (int r = 0; r < 8; ++r) {
      float s = 0.f;
#pragma unroll
      for (int q = 0; q < 8; ++q) s += G[r * 8 + q] * u[q];
      n2sq += u[r] * s;
    }
    float n2 = sqrtf(fmaxf(n2sq, 0.f));
    float sc2 = 2.0f * fminf(n2, 1.5f) / fmaxf(n2, 1e-7f);
#pragma unroll
    for (int r = 0; r < 8; ++r) sm.epi.cs[t][r] = sc2 * u[r];
  }
  __syncthreads();

  int colb = col0 + wn * 64 + fr;
  float biasv[4], bcol[4][8];
#pragma unroll
  for (int n = 0; n < 4; ++n) {
    biasv[n] = bias[colb + n * 16];
#pragma unroll
    for (int r = 0; r < 8; ++r) bcol[n][r] = sm.epi.bs2[r][wn * 64 + fr + n * 16];
  }
#pragma unroll
  for (int m = 0; m < 8; ++m) {
#pragma unroll
    for (int j = 0; j < 4; ++j) {
      int rl = wm * 128 + m * 16 + hi * 4 + j;
      float c0 = sm.epi.cs[rl][0], c1 = sm.epi.cs[rl][1], c2 = sm.epi.cs[rl][2],
            c3 = sm.epi.cs[rl][3], c4 = sm.epi.cs[rl][4], c5 = sm.epi.cs[rl][5],
            c6 = sm.epi.cs[rl][6], c7 = sm.epi.cs[rl][7];
      float* orow = out + (size_t)(row0 + rl) * DD + colb;
#pragma unroll
      for (int n = 0; n < 4; ++n) {
        float delta = c0 * bcol[n][0] + c1 * bcol[n][1] + c2 * bcol[n][2] +
                      c3 * bcol[n][3] + c4 * bcol[n][4] + c5 * bcol[n][5] +
                      c6 * bcol[n][6] + c7 * bcol[n][7];
        orow[n * 16] = acc[m][n][j] + biasv[n] + delta;
      }
    }
  }
}

extern "C" void kernel_launch(void* const* d_in, const int* in_sizes, int n_in,
                              void* d_out, int out_size, void* d_ws, size_t ws_size,
                              hipStream_t stream) {
  const float* x = (const float*)d_in[0];   // [4,2048,4096]
  const float* W = (const float*)d_in[1];   // [4096,4096]
  const float* b = (const float*)d_in[2];   // [4096]
  const float* A = (const float*)d_in[3];   // [4096,8]
  const float* Bm = (const float*)d_in[4];  // [8,4096]
  // d_in[5] = log_K : K cancels analytically, unused.
  float* out = (float*)d_out;

  char* ws = (char*)d_ws;
  __bf16* Xb = (__bf16*)ws;                                    // 64 MB
  __bf16* Wb = (__bf16*)(ws + (size_t)64 * 1024 * 1024);       // 32 MB
  float* U = (float*)(ws + (size_t)96 * 1024 * 1024);          // 256 KB
  float* G = (float*)(ws + (size_t)96 * 1024 * 1024 + 256 * 1024);

  k_prep<<<1 + 8192 + 8192, 256, 0, stream>>>(x, W, A, Bm, Xb, Wb, U, G);
  k_gemm<<<(MR / BM) * (DD / BN), 512, 0, stream>>>(Xb, Wb, b, U, G, Bm, out);
}